// Round 12
// baseline (490.068 us; speedup 1.0000x reference)
//
#include <hip/hip_runtime.h>
#include <utility>

// Problem constants: N=262144 rows, NX=NQ=64, NU=16, fp32.
#define NROWS 262144
#define BT 512                 // threads/block (8 waves)
#define RPB 256                // rows/block (= 64 octets * 4 rows each)

typedef float f8v __attribute__((ext_vector_type(8)));
typedef float f2v __attribute__((ext_vector_type(2)));

// d_ws layout (floats) — two contiguous 9280-float phase blocks:
//  phase1 @0    : C1T[4096] | D11T[4096] | D12T[1024] | bv[64]
//  phase2 @9280 : AT [4096] | B1T [4096] | B2T [1024] | bx[64]
//  C1T[j*64+i]=C1[i][j]  D11T[i*64+k]=D11[k][i] (zeros at k<=i come from input)
//  D12T[j*64+i]=D12[i][j]  AT[j*64+k]=A[k][j]  B1T[i*64+k]=B1[k][i]
//  B2T[j*64+k]=B2[k][j]
// Fused kernel stages ONE 37.12 KB phase block at a time (overlay).
//
// R=4 (r10/r11 diagnosis): kernel is LDS-unit bound; traffic per row-step =
// 256B/R. r11 proved the R=4 octet geometry (fragments 32/32/32/8, 56 VGPR,
// verified correct) but its ds_swizzle broadcasts moved the broadcast to the
// SAME saturated DS pipe (222 us). This round: identical geometry, broadcast
// reimplemented as 2 DPP ops (VALU pipe) -> DS load drops to 576 b128/wave
// (~60 us/CU) and VALU (~84 us) becomes the binding pipe.

__global__ void prep_kernel(const float* __restrict__ A, const float* __restrict__ B1,
                            const float* __restrict__ B2, const float* __restrict__ C1,
                            const float* __restrict__ D11, const float* __restrict__ D12,
                            const float* __restrict__ bv, const float* __restrict__ bx,
                            float* __restrict__ ws) {
    int g = blockIdx.x * 256 + threadIdx.x;
    if (g < 4096) {
        int r = g >> 6, c = g & 63;       // source row r, col c (64x64 row-major)
        int to = c * 64 + r;
        ws[0     + to] = C1[g];           // C1T
        ws[4096  + to] = D11[g];          // D11T
        ws[9280  + to] = A[g];            // AT
        ws[13376 + to] = B1[g];           // B1T
    }
    if (g < 1024) {
        int r = g >> 4, c = g & 15;       // 64x16 row-major source
        int to = c * 64 + r;
        ws[8192  + to] = D12[g];          // D12T
        ws[17472 + to] = B2[g];           // B2T
    }
    if (g < 64) {
        ws[9216  + g] = bv[g];
        ws[18496 + g] = bx[g];
    }
}

__device__ __forceinline__ f8v lds8(const float* p) { return *(const f8v*)p; }

// Pin pass boundaries (r6: +70 us): stops cross-pass live-range extension.
__device__ __forceinline__ void fence_sched() { __builtin_amdgcn_sched_barrier(0); }

// Octet broadcast, PURE VALU (2 DPP ops — replaces r11's ds_swizzle which
// hammered the saturated DS pipe):
//  1) quad_perm[q,q,q,q] with q = O&3: every quad now holds its own quad's
//     copy of element q in all 4 lanes.
//  2) bank-masked row_ror copies the OWNER quad's value across to the other
//     quad of the same octet; banks of owner parity keep their value (old).
//     O<4 (owner low quad):  row_ror:4  (lanes 4-7<-0-3, 12-15<-8-11), bank_mask 0xA
//     O>=4 (owner high quad): row_ror:12 (lanes 0-3<-4-7, 8-11<-12-15), bank_mask 0x5
// All controls compile-time; rows (16-lane) of wave64 behave identically.
template<int O>
__device__ __forceinline__ float obcast(float v) {
    int b = __builtin_amdgcn_update_dpp(0, __float_as_int(v),
                                        (O & 3) * 0x55, 0xF, 0xF, true);
    b = __builtin_amdgcn_update_dpp(b, b,
                                    (O < 4) ? 0x124 : 0x12C,   // row_ror:4 / :12
                                    0xF, (O < 4) ? 0xA : 0x5, false);
    return __int_as_float(b);
}

// Substitution step I, 4 rows sharing the D11T column chunk.
// Owner lane (octet lane I>>3) holds pre-activation s[I&7]; broadcast, relu,
// uniform FMA (zeros in D11T column I make non-future entries no-ops),
// owner finalizes its element.
template<int I>
__device__ __forceinline__ void substep4(f8v& s0, f8v& s1, f8v& s2, f8v& s3,
                                         const float* D11s, int c8, int c) {
    const float w0 = fmaxf(obcast<(I >> 3)>(s0[I & 7]), 0.0f);
    const float w1 = fmaxf(obcast<(I >> 3)>(s1[I & 7]), 0.0f);
    const float w2 = fmaxf(obcast<(I >> 3)>(s2[I & 7]), 0.0f);
    const float w3 = fmaxf(obcast<(I >> 3)>(s3[I & 7]), 0.0f);
    const f8v m = lds8(D11s + I * 64 + c8);        // D11T[I][I]==0, owner-safe
    s0 += m * w0;  s1 += m * w1;  s2 += m * w2;  s3 += m * w3;
    s0[I & 7] = (c == (I >> 3)) ? w0 : s0[I & 7];
    s1[I & 7] = (c == (I >> 3)) ? w1 : s1[I & 7];
    s2[I & 7] = (c == (I >> 3)) ? w2 : s2[I & 7];
    s3[I & 7] = (c == (I >> 3)) ? w3 : s3[I & 7];
}
template<int... Is>
__device__ __forceinline__ void subst_all4(f8v& s0, f8v& s1, f8v& s2, f8v& s3,
                                           const float* D11s, int c8, int c,
                                           std::integer_sequence<int, Is...>) {
    (substep4<Is>(s0, s1, s2, s3, D11s, c8, c), ...);
}

// 64-dim matvec, 4 rows: one 32B matrix chunk feeds all 4 rows' FMAs;
// multiplier scalar for row g broadcast from octet lane J>>3, elem J&7.
template<int J>
__device__ __forceinline__ void mv64step4(f8v& a0, f8v& a1, f8v& a2, f8v& a3,
                                          const float* Ms, int c8,
                                          const f8v& f0, const f8v& f1,
                                          const f8v& f2, const f8v& f3) {
    const f8v m = lds8(Ms + J * 64 + c8);
    a0 += m * obcast<(J >> 3)>(f0[J & 7]);
    a1 += m * obcast<(J >> 3)>(f1[J & 7]);
    a2 += m * obcast<(J >> 3)>(f2[J & 7]);
    a3 += m * obcast<(J >> 3)>(f3[J & 7]);
}
template<int... Js>
__device__ __forceinline__ void mv64_4(f8v& a0, f8v& a1, f8v& a2, f8v& a3,
                                       const float* Ms, int c8,
                                       const f8v& f0, const f8v& f1,
                                       const f8v& f2, const f8v& f3,
                                       std::integer_sequence<int, Js...>) {
    (mv64step4<Js>(a0, a1, a2, a3, Ms, c8, f0, f1, f2, f3), ...);
}

// 16-dim matvec, 4 rows (u fragments: 2 floats/lane/row; owner lane J>>1).
template<int J>
__device__ __forceinline__ void mv16step4(f8v& a0, f8v& a1, f8v& a2, f8v& a3,
                                          const float* Ms, int c8,
                                          const f2v& f0, const f2v& f1,
                                          const f2v& f2, const f2v& f3) {
    const f8v m = lds8(Ms + J * 64 + c8);
    a0 += m * obcast<(J >> 1)>(f0[J & 1]);
    a1 += m * obcast<(J >> 1)>(f1[J & 1]);
    a2 += m * obcast<(J >> 1)>(f2[J & 1]);
    a3 += m * obcast<(J >> 1)>(f3[J & 1]);
}
template<int... Js>
__device__ __forceinline__ void mv16_4(f8v& a0, f8v& a1, f8v& a2, f8v& a3,
                                       const float* Ms, int c8,
                                       const f2v& f0, const f2v& f1,
                                       const f2v& f2, const f2v& f3,
                                       std::integer_sequence<int, Js...>) {
    (mv16step4<Js>(a0, a1, a2, a3, Ms, c8, f0, f1, f2, f3), ...);
}

// Fused kernel: octet (8 lanes) per FOUR rows (oct, oct+64, oct+128, oct+192
// within the block's 256 rows); each lane owns an 8-output chunk per row.
// Overlay staging (37.12 KB). Pass order = round-7/10 register discipline:
//   stage p1; 1. s = bv + C1 x + D12 u  [xf, uf die]
//   2. substitution s -> w
//   overlay p2 (live: s only)
//   3. acc = bx + B1 w                  [s dies]
//   4. reload x,u; acc += Ax + B2u
// launch_bounds arg=3 (measured model cap=256/arg ~85): r11 compiled this
// exact register shape at 56 VGPR, no spill.
__global__ __launch_bounds__(BT, 3) void renl2_fused(const float* __restrict__ x,
                                                     const float* __restrict__ u,
                                                     const float* __restrict__ ws,
                                                     float* __restrict__ out) {
    __shared__ __align__(64) float sm[9280];    // 37.12 KB
    const int tid = threadIdx.x;
    const int c   = tid & 7;              // lane within octet
    const int c8  = c << 3;               // 8-float chunk offset
    const int oct = tid >> 3;             // octet id = base row within block
    const size_t row0 = (size_t)blockIdx.x * RPB;   // rows [row0, row0+256)

    // ---- per-lane x/u fragments, 4 rows each (fully coalesced) ----
    const float* xb = x + (row0 + oct) * 64 + c8;
    const float* ub = u + (row0 + oct) * 16 + (c << 1);
    const f8v xf0 = *(const f8v*)(xb);
    const f8v xf1 = *(const f8v*)(xb + 64 * 64);
    const f8v xf2 = *(const f8v*)(xb + 128 * 64);
    const f8v xf3 = *(const f8v*)(xb + 192 * 64);
    const f2v uf0 = *(const f2v*)(ub);
    const f2v uf1 = *(const f2v*)(ub + 64 * 16);
    const f2v uf2 = *(const f2v*)(ub + 128 * 16);
    const f2v uf3 = *(const f2v*)(ub + 192 * 16);

    // ---- stage phase-1 table (2320 float4) ----
    const float4* wsv = (const float4*)ws;
    float4* smv = (float4*)sm;
#pragma unroll
    for (int i = 0; i < 4; i++) smv[tid + i * BT] = wsv[tid + i * BT];
    if (tid < 2320 - 4 * BT) smv[tid + 4 * BT] = wsv[tid + 4 * BT];
    __syncthreads();

    // ---- pass 1: s = bv + C1 x + D12 u   (xf, uf die here) ----
    f8v s0 = lds8(sm + 9216 + c8);
    f8v s1 = s0, s2 = s0, s3 = s0;
    mv64_4(s0, s1, s2, s3, sm + 0,    c8, xf0, xf1, xf2, xf3,
           std::make_integer_sequence<int, 64>{});
    mv16_4(s0, s1, s2, s3, sm + 8192, c8, uf0, uf1, uf2, uf3,
           std::make_integer_sequence<int, 16>{});
    fence_sched();

    // ---- pass 2: substitution (octet DPP broadcast, branchless, VALU) ----
    subst_all4(s0, s1, s2, s3, sm + 4096, c8, c,
               std::make_integer_sequence<int, 64>{});
    fence_sched();

    // ---- overlay: phase-2 table (live regs: s only) ----
    __syncthreads();
#pragma unroll
    for (int i = 0; i < 4; i++) smv[tid + i * BT] = wsv[2320 + tid + i * BT];
    if (tid < 2320 - 4 * BT) smv[tid + 4 * BT] = wsv[2320 + tid + 4 * BT];
    __syncthreads();
    // local layout now: AT@0 | B1T@4096 | B2T@8192 | bx@9216

    // ---- pass 3: acc = bx + B1 w   (s dies here) ----
    f8v acc0 = lds8(sm + 9216 + c8);
    f8v acc1 = acc0, acc2 = acc0, acc3 = acc0;
    mv64_4(acc0, acc1, acc2, acc3, sm + 4096, c8, s0, s1, s2, s3,
           std::make_integer_sequence<int, 64>{});
    fence_sched();

    // ---- pass 4: reload x/u (L3-hot; laundered so pass-1 loads can't be
    //      CSE-forwarded and resurrect their live ranges), acc += Ax + B2u ----
    size_t r0 = row0;
    asm volatile("" : "+s"(r0));          // opaque: forces a true reload
    const float* xb2 = x + (r0 + oct) * 64 + c8;
    const float* ub2 = u + (r0 + oct) * 16 + (c << 1);
    const f8v xg0 = *(const f8v*)(xb2);
    const f8v xg1 = *(const f8v*)(xb2 + 64 * 64);
    const f8v xg2 = *(const f8v*)(xb2 + 128 * 64);
    const f8v xg3 = *(const f8v*)(xb2 + 192 * 64);
    const f2v ug0 = *(const f2v*)(ub2);
    const f2v ug1 = *(const f2v*)(ub2 + 64 * 16);
    const f2v ug2 = *(const f2v*)(ub2 + 128 * 16);
    const f2v ug3 = *(const f2v*)(ub2 + 192 * 16);
    mv64_4(acc0, acc1, acc2, acc3, sm + 0,    c8, xg0, xg1, xg2, xg3,
           std::make_integer_sequence<int, 64>{});
    mv16_4(acc0, acc1, acc2, acc3, sm + 8192, c8, ug0, ug1, ug2, ug3,
           std::make_integer_sequence<int, 16>{});

    // ---- four 32B stores: x_dot for the 4 rows ----
    float* ob = out + (row0 + oct) * 64 + c8;
    *(f8v*)(ob)            = acc0;
    *(f8v*)(ob + 64 * 64)  = acc1;
    *(f8v*)(ob + 128 * 64) = acc2;
    *(f8v*)(ob + 192 * 64) = acc3;
}

extern "C" void kernel_launch(void* const* d_in, const int* in_sizes, int n_in,
                              void* d_out, int out_size, void* d_ws, size_t ws_size,
                              hipStream_t stream) {
    const float* x   = (const float*)d_in[0];
    const float* u   = (const float*)d_in[1];
    const float* A   = (const float*)d_in[2];
    const float* B1  = (const float*)d_in[3];
    const float* B2  = (const float*)d_in[4];
    const float* C1  = (const float*)d_in[5];
    const float* D11 = (const float*)d_in[6];
    const float* D12 = (const float*)d_in[7];
    const float* bv  = (const float*)d_in[8];
    const float* bx  = (const float*)d_in[9];
    float* out = (float*)d_out;
    float* ws  = (float*)d_ws;

    prep_kernel<<<16, 256, 0, stream>>>(A, B1, B2, C1, D11, D12, bv, bx, ws);
    renl2_fused<<<NROWS / RPB, BT, 0, stream>>>(x, u, ws, out);
}

// Round 14
// 242.207 us; speedup vs baseline: 2.0233x; 2.0233x over previous
//
#include <hip/hip_runtime.h>
#include <utility>

// Problem constants: N=262144 rows, NX=NQ=64, NU=16, fp32.
#define NROWS 262144
#define BT 512                 // threads/block (8 waves)
#define RPB 256                // rows/block (= BT/4 quads * 2 rows each)

typedef float f16v __attribute__((ext_vector_type(16)));
typedef float f4v  __attribute__((ext_vector_type(4)));
typedef float f2v  __attribute__((ext_vector_type(2)));

// 16-float row fragment as 8 packed fp32 pairs (same 16 VGPRs as f16v) —
// feeds v_pk_fma_f32 (VOP3P packed math: 2 fp32 FMA per instruction,
// halving the FMA issue-cycle count that r10's 84us VALU time is made of).
struct r8 { f2v p[8]; };

// d_ws layout (floats) — two contiguous 9280-float phase blocks:
//  phase1 @0    : C1T[4096] | D11T[4096] | D12T[1024] | bv[64]
//  phase2 @9280 : AT [4096] | B1T [4096] | B2T [1024] | bx[64]
//  C1T[j*64+i]=C1[i][j]  D11T[i*64+k]=D11[k][i] (zeros at k<=i come from input)
//  D12T[j*64+i]=D12[i][j]  AT[j*64+k]=A[k][j]  B1T[i*64+k]=B1[k][i]
//  B2T[j*64+k]=B2[k][j]
// Fused kernel stages ONE 37.12 KB phase block at a time (overlay) ->
// 4 blocks/CU. R=2 quad geometry (r10 engine, 131us, VGPR 52, no spill).
// NOTE (r13): v_pk_max_f32 does NOT exist on gfx950 — deferred relu uses
// scalar v_max_f32 (32 instrs/thread, negligible). v_pk_fma_f32 assembles.

__global__ void prep_kernel(const float* __restrict__ A, const float* __restrict__ B1,
                            const float* __restrict__ B2, const float* __restrict__ C1,
                            const float* __restrict__ D11, const float* __restrict__ D12,
                            const float* __restrict__ bv, const float* __restrict__ bx,
                            float* __restrict__ ws) {
    int g = blockIdx.x * 256 + threadIdx.x;
    if (g < 4096) {
        int r = g >> 6, c = g & 63;       // source row r, col c (64x64 row-major)
        int to = c * 64 + r;
        ws[0     + to] = C1[g];           // C1T
        ws[4096  + to] = D11[g];          // D11T
        ws[9280  + to] = A[g];            // AT
        ws[13376 + to] = B1[g];           // B1T
    }
    if (g < 1024) {
        int r = g >> 4, c = g & 15;       // 64x16 row-major source
        int to = c * 64 + r;
        ws[8192  + to] = D12[g];          // D12T
        ws[17472 + to] = B2[g];           // B2T
    }
    if (g < 64) {
        ws[9216  + g] = bv[g];
        ws[18496 + g] = bx[g];
    }
}

__device__ __forceinline__ f16v lds16(const float* p) { return *(const f16v*)p; }
__device__ __forceinline__ r8  lds16p(const float* p) {
    return __builtin_bit_cast(r8, *(const f16v*)p);
}

// Pin pass boundaries (r6: +70 us): stops cross-pass live-range extension.
__device__ __forceinline__ void fence_sched() { __builtin_amdgcn_sched_barrier(0); }

// Quad-lane broadcast via DPP quad_perm:[Q,Q,Q,Q] — pure VALU (~2 cyc).
template<int Q>
__device__ __forceinline__ float qbcast(float v) {
    return __int_as_float(__builtin_amdgcn_update_dpp(
        0, __float_as_int(v), Q * 0x55, 0xF, 0xF, true));
}

// a.p[k] += m.p[k] * (s,s) as 8 v_pk_fma_f32 — 2 fp32 FMA per instruction
// (per-half IEEE fma, numerically identical to the contracted v_fmac path).
__device__ __forceinline__ void pkfma8(r8& a, const f16v m, const float s) {
    const r8 mp = __builtin_bit_cast(r8, m);
    f2v ss; ss[0] = s; ss[1] = s;
#pragma unroll
    for (int k = 0; k < 8; k++)
        asm("v_pk_fma_f32 %0, %1, %2, %0" : "+v"(a.p[k]) : "v"(mp.p[k]), "v"(ss));
}

// Deferred relu: a = max(a, 0) — SCALAR v_max_f32 (no packed max on gfx950).
// Replaces r10's per-step owner cndmask (128/wave): D11's strict-lower zeros
// keep the owner's element at pre-activation through the whole substitution,
// so one relu pass at the end produces exactly the same w vector.
__device__ __forceinline__ void relu8(r8& a) {
#pragma unroll
    for (int k = 0; k < 8; k++) {
        a.p[k][0] = fmaxf(a.p[k][0], 0.0f);
        a.p[k][1] = fmaxf(a.p[k][1], 0.0f);
    }
}

// Compile-time element access into the pair array (all call sites pass
// template constants -> static indexing, no scratch).
template<int E>
__device__ __forceinline__ float getel(const r8& a) { return a.p[E >> 1][E & 1]; }

// Substitution step I, two rows sharing the D11T column. Broadcast the
// owner lane's PRE-activation element, relu on every lane, uniform pk-FMA
// (zeros in D11T column I make non-future entries exact no-ops; the owner's
// own element is untouched since D11T[I][I]==0 — no finalize needed).
template<int I>
__device__ __forceinline__ void substep2(r8& s0, r8& s1, const float* D11s, int c16) {
    const float w0 = fmaxf(qbcast<(I >> 4)>(getel<(I & 15)>(s0)), 0.0f);
    const float w1 = fmaxf(qbcast<(I >> 4)>(getel<(I & 15)>(s1)), 0.0f);
    const f16v m = lds16(D11s + I * 64 + c16);
    pkfma8(s0, m, w0);
    pkfma8(s1, m, w1);
}
template<int... Is>
__device__ __forceinline__ void subst_all2(r8& s0, r8& s1, const float* D11s,
                                           int c16, std::integer_sequence<int, Is...>) {
    (substep2<Is>(s0, s1, D11s, c16), ...);
}

// 64-dim matvec, two rows: matrix chunk loaded once (4x ds_read_b128),
// multiplier scalars quad-distributed and DPP-broadcast, packed FMA.
template<int J>
__device__ __forceinline__ void mv64step2(r8& a0, r8& a1, const float* Ms,
                                          int c16, const r8& f0, const r8& f1) {
    const f16v m = lds16(Ms + J * 64 + c16);
    pkfma8(a0, m, qbcast<(J >> 4)>(getel<(J & 15)>(f0)));
    pkfma8(a1, m, qbcast<(J >> 4)>(getel<(J & 15)>(f1)));
}
template<int... Js>
__device__ __forceinline__ void mv64_2(r8& a0, r8& a1, const float* Ms, int c16,
                                       const r8& f0, const r8& f1,
                                       std::integer_sequence<int, Js...>) {
    (mv64step2<Js>(a0, a1, Ms, c16, f0, f1), ...);
}

// 16-dim matvec, two rows (u fragments: 4 floats/lane/row).
template<int J>
__device__ __forceinline__ void mv16step2(r8& a0, r8& a1, const float* Ms,
                                          int c16, const f4v& f0, const f4v& f1) {
    const f16v m = lds16(Ms + J * 64 + c16);
    pkfma8(a0, m, qbcast<(J >> 2)>(f0[J & 3]));
    pkfma8(a1, m, qbcast<(J >> 2)>(f1[J & 3]));
}
template<int... Js>
__device__ __forceinline__ void mv16_2(r8& a0, r8& a1, const float* Ms, int c16,
                                       const f4v& f0, const f4v& f1,
                                       std::integer_sequence<int, Js...>) {
    (mv16step2<Js>(a0, a1, Ms, c16, f0, f1), ...);
}

// Fused kernel: quad (4 lanes) per TWO rows (row q and row q+128); each lane
// owns a 16-output chunk of each. ONE phase table LDS-resident at a time
// (overlay): 37.12 KB -> 4 blocks/CU = 32 waves/CU.
// Pass order caps fragment liveness (round-7/10-proven 64-VGPR schedule):
//   stage p1; 1. s = bv + C1 x + D12 u  [xf, uf die]
//   2. substitution s -> pre-act; deferred relu -> w
//   overlay p2 (live: s only)
//   3. acc = bx + B1 w                  [s dies]
//   4. reload x,u; acc += Ax + B2u
__global__ __launch_bounds__(BT, 4) void renl2_fused(const float* __restrict__ x,
                                                     const float* __restrict__ u,
                                                     const float* __restrict__ ws,
                                                     float* __restrict__ out) {
    __shared__ __align__(64) float sm[9280];    // 37.12 KB -> 4 blocks/CU
    const int tid = threadIdx.x;
    const int c16 = (tid & 3) << 4;       // quad chunk offset
    const size_t row0 = (size_t)blockIdx.x * RPB;   // rows [row0, row0+256)

    // ---- per-lane x/u fragments for both rows (fully coalesced) ----
    const r8  xf0 = lds16p(x + row0 * 64 + (size_t)tid * 16);
    const r8  xf1 = lds16p(x + (row0 + 128) * 64 + (size_t)tid * 16);
    const f4v uf0 = *(const f4v*)(u + row0 * 16 + (size_t)tid * 4);
    const f4v uf1 = *(const f4v*)(u + (row0 + 128) * 16 + (size_t)tid * 4);

    // ---- stage phase-1 table (2320 float4) ----
    const float4* wsv = (const float4*)ws;
    float4* smv = (float4*)sm;
#pragma unroll
    for (int i = 0; i < 4; i++) smv[tid + i * BT] = wsv[tid + i * BT];
    if (tid < 2320 - 4 * BT) smv[tid + 4 * BT] = wsv[tid + 4 * BT];
    __syncthreads();

    // ---- pass 1: s = bv + C1 x + D12 u   (xf, uf die here) ----
    r8 s0 = lds16p(sm + 9216 + c16);
    r8 s1 = s0;
    mv64_2(s0, s1, sm + 0,    c16, xf0, xf1, std::make_integer_sequence<int, 64>{});
    mv16_2(s0, s1, sm + 8192, c16, uf0, uf1, std::make_integer_sequence<int, 16>{});
    fence_sched();

    // ---- pass 2: substitution + deferred relu (s -> w) ----
    subst_all2(s0, s1, sm + 4096, c16, std::make_integer_sequence<int, 64>{});
    relu8(s0);
    relu8(s1);
    fence_sched();

    // ---- overlay: phase-2 table (live regs: s only) ----
    __syncthreads();
#pragma unroll
    for (int i = 0; i < 4; i++) smv[tid + i * BT] = wsv[2320 + tid + i * BT];
    if (tid < 2320 - 4 * BT) smv[tid + 4 * BT] = wsv[2320 + tid + 4 * BT];
    __syncthreads();
    // local layout now: AT@0 | B1T@4096 | B2T@8192 | bx@9216

    // ---- pass 3: acc = bx + B1 w   (s dies here) ----
    r8 acc0 = lds16p(sm + 9216 + c16);
    r8 acc1 = acc0;
    mv64_2(acc0, acc1, sm + 4096, c16, s0, s1, std::make_integer_sequence<int, 64>{});
    fence_sched();

    // ---- pass 4: reload x/u (L3-hot; laundered so pass-1 loads can't be
    //      CSE-forwarded and resurrect their live ranges), acc += Ax + B2u ----
    size_t r0 = row0;
    asm volatile("" : "+s"(r0));          // opaque: forces a true reload
    const r8  xg0 = lds16p(x + r0 * 64 + (size_t)tid * 16);
    const r8  xg1 = lds16p(x + (r0 + 128) * 64 + (size_t)tid * 16);
    const f4v ug0 = *(const f4v*)(u + r0 * 16 + (size_t)tid * 4);
    const f4v ug1 = *(const f4v*)(u + (r0 + 128) * 16 + (size_t)tid * 4);
    mv64_2(acc0, acc1, sm + 0,    c16, xg0, xg1, std::make_integer_sequence<int, 64>{});
    mv16_2(acc0, acc1, sm + 8192, c16, ug0, ug1, std::make_integer_sequence<int, 16>{});

    // ---- two 64B stores: x_dot for both rows ----
    const size_t q = (size_t)(tid >> 2);
    *(f16v*)(out + (row0 + q) * 64 + c16)       = __builtin_bit_cast(f16v, acc0);
    *(f16v*)(out + (row0 + 128 + q) * 64 + c16) = __builtin_bit_cast(f16v, acc1);
}

extern "C" void kernel_launch(void* const* d_in, const int* in_sizes, int n_in,
                              void* d_out, int out_size, void* d_ws, size_t ws_size,
                              hipStream_t stream) {
    const float* x   = (const float*)d_in[0];
    const float* u   = (const float*)d_in[1];
    const float* A   = (const float*)d_in[2];
    const float* B1  = (const float*)d_in[3];
    const float* B2  = (const float*)d_in[4];
    const float* C1  = (const float*)d_in[5];
    const float* D11 = (const float*)d_in[6];
    const float* D12 = (const float*)d_in[7];
    const float* bv  = (const float*)d_in[8];
    const float* bx  = (const float*)d_in[9];
    float* out = (float*)d_out;
    float* ws  = (float*)d_ws;

    prep_kernel<<<16, 256, 0, stream>>>(A, B1, B2, C1, D11, D12, bv, bx, ws);
    renl2_fused<<<NROWS / RPB, BT, 0, stream>>>(x, u, ws, out);
}